// Round 4
// baseline (561.494 us; speedup 1.0000x reference)
//
#include <hip/hip_runtime.h>

// sbvr decode: decoded[g,l] = sum_s coeff_cache[coeff_idx[g], s] * ((bvr[g,s]>>l)&1)
// G = 4,194,304 groups, S = 4 sums, L = 16 elements/group, out = 64M fp32 (256 MB).
//
// v5: DIAGNOSTIC (repeat-3). Four structural experiments (MLP batching,
// store-path, two-pass gather quarantine) were all neutral; every roofline
// model (bytes, VMEM issue rate, gather transaction rate) says ~55 us, yet
// the controllable portion of dur_us is stuck at ~150 us. The decode kernel
// has never appeared in the top-5 counter table (all slots taken by 164-169us
// harness poison fills), so every theory so far was tested against an
// INFERRED decomposition. This version executes the v0 body 3x per thread
// over rotated bijective index sets:
//   t_r = (t0 + r*OFF) & (2^24 - 1),  OFF % 4 == 0
// - each repeat covers every output element exactly once with the same value
//   (idempotent -> passes verification; benign same-value races between
//   repeats of different blocks)
// - OFF uniform across a wave -> coalescing and group-merge geometry
//   identical to v0 in every repeat
// - dispatch time ~ 3*T_kernel > 180 us -> guaranteed top-1 in the counter
//   table: first direct read of FETCH_SIZE / WRITE_SIZE / hbm_gbps for this
//   kernel. Also dur_us - 343 = 2*T_kernel, pinning T_kernel exactly.
//
// NOTE: __builtin_nontemporal_* requires native ext_vector_type, not the
// HIP_vector_type structs (int4/float4) — hence i32x4/f32x4 below.

#define NUM_SUMS 4
#define BVR_LEN 16

typedef int   i32x4 __attribute__((ext_vector_type(4)));
typedef float f32x4 __attribute__((ext_vector_type(4)));

static constexpr int THREADS_TOTAL = (8192 * 8192) / 4;  // 16,777,216 items, 4 elems each
static constexpr int BLOCK   = 256;
static constexpr int REPEATS = 3;
static constexpr int OFF     = 0x555554;                 // rotation per repeat, %4==0

__global__ __launch_bounds__(BLOCK) void sbvr_decode_kernel(
        const float* __restrict__ coeff_cache,   // [65536, 4]
        const int*   __restrict__ coeff_idx,     // [G]
        const int*   __restrict__ bvr,           // [G, 4]
        float*       __restrict__ out)           // [G * 16]
{
    const int t0 = blockIdx.x * BLOCK + threadIdx.x;

#pragma unroll 1
    for (int r = 0; r < REPEATS; ++r) {
        const int t = (t0 + r * OFF) & (THREADS_TOTAL - 1);
        const int g = t >> 2;        // group
        const int q = t & 3;         // quarter within group

        // Streaming reads: nontemporal (no reuse beyond in-wave broadcast).
        const int   idx = __builtin_nontemporal_load(coeff_idx + g);
        const i32x4 b   = __builtin_nontemporal_load((const i32x4*)bvr + g);

        // Table gather: normal cached load -> L2-resident (1 MB table).
        const f32x4 c = ((const f32x4*)coeff_cache)[idx];

        const int base = q * 4;      // first bit index this thread handles
        f32x4 rr;
#pragma unroll
        for (int j = 0; j < 4; ++j) {
            const int l = base + j;
            // accumulate in the reference's s-order (s = 0..3) in fp32
            float acc = ((b.x >> l) & 1) ? c.x : 0.0f;
            acc      += ((b.y >> l) & 1) ? c.y : 0.0f;
            acc      += ((b.z >> l) & 1) ? c.z : 0.0f;
            acc      += ((b.w >> l) & 1) ? c.w : 0.0f;
            rr[j] = acc;
        }
        __builtin_nontemporal_store(rr, (f32x4*)out + t);
    }
}

extern "C" void kernel_launch(void* const* d_in, const int* in_sizes, int n_in,
                              void* d_out, int out_size, void* d_ws, size_t ws_size,
                              hipStream_t stream) {
    const float* coeff_cache = (const float*)d_in[0];
    const int*   coeff_idx   = (const int*)d_in[1];
    const int*   bvr         = (const int*)d_in[2];
    float*       out         = (float*)d_out;

    const int grid = THREADS_TOTAL / BLOCK;  // 65536 blocks
    sbvr_decode_kernel<<<grid, BLOCK, 0, stream>>>(coeff_cache, coeff_idx, bvr, out);
}

// Round 5
// 331.539 us; speedup vs baseline: 1.6936x; 1.6936x over previous
//
#include <hip/hip_runtime.h>

// sbvr decode: decoded[g,l] = sum_s coeff_cache[coeff_idx[g], s] * ((bvr[g,s]>>l)&1)
// G = 4,194,304 groups, S = 4 sums, L = 16 elements/group, out = 64M fp32 (256 MB).
//
// v6: WAVE-COOPERATIVE STAGING. v5's repeat-3 diagnostic finally exposed the
// kernel's counters: hbm 3.06 TB/s (38% peak), FETCH = compulsory (gather is
// >=92% cache-hit -> no traffic inflation), WRITE = compulsory, VALUBusy 26%,
// occupancy 83%, and 4x MLP was null (v2). Only surviving model: VMEM
// ADDRESS-ISSUE bound. v0 spends 16 lane-addresses per group (idx, bvr, and
// gather each issued by 4 lanes redundantly since 4 quarter-group threads
// share one group; + 4 store lanes) ~= 268K TA-cycles/CU at 1 addr/cy vs the
// 252K-cycle kernel: saturated.
//
// Fix: per block of 256 threads, stage 256 groups cooperatively:
//   Phase A: thread tid handles group g0+tid alone -> 1 clean idx lane-addr,
//            1 clean 16B bvr lane-addr, 1 gather lane-addr per group (256
//            independent gathers in flight per block), parked in 8 KB LDS.
//   Phase B: 4 passes; thread t computes quarter-group (p*64 + (t>>2), t&3)
//            reading c/b from LDS (4-lane-broadcast is free in LDS), storing
//            one contiguous float4 -> out4[g0*4 + p*256 + t] (4 KB/wave,
//            identical coalescing to v0).
// Lane-addresses per group: 16 -> 7. Predicted T_k 104 -> ~55-65 us
// (dur_us ~= 238 us harness overhead + T_k -> ~295-305).
//
// NOTE: __builtin_nontemporal_* requires native ext_vector_type, not the
// HIP_vector_type structs (int4/float4) — hence i32x4/f32x4 below.

#define NUM_SUMS 4
#define BVR_LEN 16

typedef int   i32x4 __attribute__((ext_vector_type(4)));
typedef float f32x4 __attribute__((ext_vector_type(4)));

static constexpr int NUM_GROUPS = (8192 * 8192) / 16;  // 4,194,304
static constexpr int BLOCK      = 256;
static constexpr int G_BLK      = 256;                 // groups staged per block
static constexpr int GRID       = NUM_GROUPS / G_BLK;  // 16,384 blocks

__global__ __launch_bounds__(BLOCK) void sbvr_decode_kernel(
        const float* __restrict__ coeff_cache,   // [65536, 4]
        const int*   __restrict__ coeff_idx,     // [G]
        const int*   __restrict__ bvr,           // [G, 4]
        float*       __restrict__ out)           // [G * 16]
{
    __shared__ f32x4 lds_c[G_BLK];   // gathered coeffs, 4 KB
    __shared__ i32x4 lds_b[G_BLK];   // bit words,        4 KB

    const int tid = threadIdx.x;
    const int g0  = blockIdx.x * G_BLK;

    // ---- Phase A: cooperative stage, one lane per group ----
    {
        const int g = g0 + tid;
        // Streams read exactly once -> nontemporal (keep table L2-resident).
        const int   idx = __builtin_nontemporal_load(coeff_idx + g);
        const i32x4 b   = __builtin_nontemporal_load((const i32x4*)bvr + g);
        // Random 16 B gather: normal cached load (1 MB table, L2-resident).
        const f32x4 c   = ((const f32x4*)coeff_cache)[idx];
        lds_c[tid] = c;
        lds_b[tid] = b;
    }
    __syncthreads();

    // ---- Phase B: 4 passes, quarter-group per thread, contiguous stores ----
#pragma unroll
    for (int p = 0; p < 4; ++p) {
        const int gl = p * 64 + (tid >> 2);   // local group
        const int q4 = (tid & 3) * 4;         // first bit index

        const f32x4 c = lds_c[gl];            // 4-lane broadcast: free
        const i32x4 b = lds_b[gl];

        f32x4 r;
#pragma unroll
        for (int j = 0; j < 4; ++j) {
            const int l = q4 + j;
            // accumulate in the reference's s-order (s = 0..3) in fp32
            float acc = ((b.x >> l) & 1) ? c.x : 0.0f;
            acc      += ((b.y >> l) & 1) ? c.y : 0.0f;
            acc      += ((b.z >> l) & 1) ? c.z : 0.0f;
            acc      += ((b.w >> l) & 1) ? c.w : 0.0f;
            r[j] = acc;
        }
        // out4 index: (g0+gl)*4 + q = g0*4 + p*256 + tid  -> contiguous 4 KB/wave
        __builtin_nontemporal_store(r, (f32x4*)out + (g0 * 4 + p * BLOCK + tid));
    }
}

extern "C" void kernel_launch(void* const* d_in, const int* in_sizes, int n_in,
                              void* d_out, int out_size, void* d_ws, size_t ws_size,
                              hipStream_t stream) {
    const float* coeff_cache = (const float*)d_in[0];
    const int*   coeff_idx   = (const int*)d_in[1];
    const int*   bvr         = (const int*)d_in[2];
    float*       out         = (float*)d_out;

    sbvr_decode_kernel<<<GRID, BLOCK, 0, stream>>>(coeff_cache, coeff_idx, bvr, out);
}